// Round 8
// baseline (402.586 us; speedup 1.0000x reference)
//
#include <hip/hip_runtime.h>
#include <math.h>

#define NN 512
#define MM (NN * NN)
#define HW (NN * NN)
#define CH 3

typedef float floatx4 __attribute__((ext_vector_type(4)));

__device__ __forceinline__ float dct_s(int k) {
    // s_0 = sqrt(1/512), s_k = sqrt(2/512)
    return (k == 0) ? 0.04419417382415922f : 0.0625f;
}

// ---------------- Stage A: T[h][wp] ----------------
// Tr[h][wp] = sum_hp D[hp][h]*att[hp][wp]*rw[hp]
// Tc[h][wp] = cw[wp] * sum_hp D[hp][h]*att[hp][wp]
__global__ void __launch_bounds__(256) k_stageA(
    const float* __restrict__ att, const float* __restrict__ rw,
    const float* __restrict__ cw, float* __restrict__ Tr, float* __restrict__ Tc,
    unsigned int* __restrict__ counter)
{
    __shared__ float sD[2048];        // [hp][i] = D[hp][h0+i], computed in-kernel
    __shared__ float sRw[512];
    __shared__ float sAcc[256 * 9];   // pad 9 -> conflict-free k-reduction
    const int tid = threadIdx.x;
    const int bx  = blockIdx.x;
    if (bx == 0 && tid == 0) *counter = 0u;   // reset for fused reduce+final
    const int h0  = (bx >> 3) * 4;
    const int wp0 = (bx & 7) * 64;
    const int kc  = tid >> 6;
    const int wl  = tid & 63;
    const int wp  = wp0 + wl;
    const int hp0 = kc * 128;

    #pragma unroll
    for (int e = 0; e < 8; ++e) {                 // 2048 D entries, 8/thread
        int idx = tid * 8 + e;
        int hp = idx >> 2, i = idx & 3;
        int m = ((2 * (h0 + i) + 1) * hp) & 2047; // exact mod 4N
        sD[idx] = dct_s(hp) * cospif((float)m * (1.0f / 1024.0f));
    }
    sRw[tid] = rw[tid];
    sRw[256 + tid] = rw[256 + tid];
    __syncthreads();

    float ar0=0.f,ar1=0.f,ar2=0.f,ar3=0.f, as0=0.f,as1=0.f,as2=0.f,as3=0.f;
    #pragma unroll 4
    for (int t = 0; t < 128; ++t) {
        int hp = hp0 + t;
        float a = att[hp * NN + wp];              // coalesced 256B/wave
        float r = sRw[hp];                        // LDS broadcast
        float4 d = *reinterpret_cast<const float4*>(&sD[hp * 4]); // broadcast
        float ra = r * a;
        ar0 += d.x * ra; as0 += d.x * a;
        ar1 += d.y * ra; as1 += d.y * a;
        ar2 += d.z * ra; as2 += d.z * a;
        ar3 += d.w * ra; as3 += d.w * a;
    }
    float* sa = &sAcc[tid * 9];
    sa[0]=ar0; sa[1]=ar1; sa[2]=ar2; sa[3]=ar3;
    sa[4]=as0; sa[5]=as1; sa[6]=as2; sa[7]=as3;
    __syncthreads();
    if (tid < 64) {
        float v[8];
        #pragma unroll
        for (int j = 0; j < 8; ++j)
            v[j] = sAcc[(0*64 + tid)*9 + j] + sAcc[(1*64 + tid)*9 + j]
                 + sAcc[(2*64 + tid)*9 + j] + sAcc[(3*64 + tid)*9 + j];
        float c = cw[wp0 + tid];
        #pragma unroll
        for (int i = 0; i < 4; ++i) {
            Tr[(h0 + i) * NN + wp0 + tid] = v[i];
            Tc[(h0 + i) * NN + wp0 + tid] = v[4 + i] * c;
        }
    }
}

// ---------------- Stage B: G[h][w] = sum_wp T[h][wp] * D[wp][w] ----------------
__global__ void __launch_bounds__(256) k_stageB(
    const float* __restrict__ Tr, const float* __restrict__ Tc,
    float* __restrict__ Gr, float* __restrict__ Gc)
{
    __shared__ float sT[512 * 8];     // [wp][0..3]=Tr(h0..h0+3), [4..7]=Tc
    __shared__ float sAcc[256 * 9];
    const int tid = threadIdx.x;
    const int bx  = blockIdx.x;
    const int h0  = (bx >> 3) * 4;
    const int w0  = (bx & 7) * 64;
    const int kc  = tid >> 6;
    const int wl  = tid & 63;
    const int w   = w0 + wl;
    const int wp0 = kc * 128;

    #pragma unroll
    for (int i = 0; i < 4; ++i) {                 // coalesced global reads
        sT[tid * 8 + i]             = Tr[(h0 + i) * NN + tid];
        sT[tid * 8 + 4 + i]         = Tc[(h0 + i) * NN + tid];
        sT[(tid + 256) * 8 + i]     = Tr[(h0 + i) * NN + tid + 256];
        sT[(tid + 256) * 8 + 4 + i] = Tc[(h0 + i) * NN + tid + 256];
    }
    __syncthreads();

    float gr0=0.f,gr1=0.f,gr2=0.f,gr3=0.f, gc0=0.f,gc1=0.f,gc2=0.f,gc3=0.f;
    const int w2 = 2 * w + 1;
    int m = (w2 * wp0) & 2047;                    // incremental phase
    #pragma unroll 4
    for (int t = 0; t < 128; ++t) {
        int wp = wp0 + t;
        float s = (wp == 0) ? 0.04419417382415922f : 0.0625f;
        float d = s * cospif((float)m * (1.0f / 1024.0f));
        m = (m + w2) & 2047;
        float4 ta = *reinterpret_cast<const float4*>(&sT[wp * 8]);     // broadcast
        float4 tb = *reinterpret_cast<const float4*>(&sT[wp * 8 + 4]); // broadcast
        gr0 += ta.x * d; gr1 += ta.y * d; gr2 += ta.z * d; gr3 += ta.w * d;
        gc0 += tb.x * d; gc1 += tb.y * d; gc2 += tb.z * d; gc3 += tb.w * d;
    }
    float* sa = &sAcc[tid * 9];
    sa[0]=gr0; sa[1]=gr1; sa[2]=gr2; sa[3]=gr3;
    sa[4]=gc0; sa[5]=gc1; sa[6]=gc2; sa[7]=gc3;
    __syncthreads();
    if (tid < 64) {
        float v[8];
        #pragma unroll
        for (int j = 0; j < 8; ++j)
            v[j] = sAcc[(0*64 + tid)*9 + j] + sAcc[(1*64 + tid)*9 + j]
                 + sAcc[(2*64 + tid)*9 + j] + sAcc[(3*64 + tid)*9 + j];
        #pragma unroll
        for (int i = 0; i < 4; ++i) {
            Gr[(h0 + i) * NN + w0 + tid] = v[i];
            Gc[(h0 + i) * NN + w0 + tid] = v[4 + i];
        }
    }
}

// ---------------- Reduce + final (fused) ----------------
// grid (32, 192): block = (ck, b*3+c). One contiguous 32KB x stream per block,
// G chunks stay L2-resident (2MB < 4MB/XCD). Max TLP: 6144 blocks.
// Last finishing block does the final fixed-order sum + sigmoid (deterministic).
__global__ void __launch_bounds__(256) k_reduce_final(
    const float* __restrict__ x, const float* __restrict__ Gr,
    const float* __restrict__ Gc, float* __restrict__ partials,
    unsigned int* __restrict__ counter, float* __restrict__ out)
{
    const int ck = blockIdx.x;        // 0..31
    const int bc = blockIdx.y;        // 0..191 = b*3 + c
    const int t  = threadIdx.x;
    const float* xp = x + (size_t)bc * HW;   // plane (b,c)
    const int hw0 = ck * (HW / 32);          // 8192-wide chunk

    float accr = 0.f, accc = 0.f;
    #pragma unroll
    for (int j = 0; j < 8; ++j) {
        int hw = hw0 + j * 1024 + t * 4;
        floatx4 xv = __builtin_nontemporal_load(
                         reinterpret_cast<const floatx4*>(xp + hw));
        float4 gr = *(const float4*)(Gr + hw);
        float4 gc = *(const float4*)(Gc + hw);
        accr += gr.x * xv.x + gr.y * xv.y + gr.z * xv.z + gr.w * xv.w;
        accc += gc.x * xv.x + gc.y * xv.y + gc.z * xv.z + gc.w * xv.w;
    }
    for (int off = 32; off > 0; off >>= 1) {
        accr += __shfl_down(accr, off);
        accc += __shfl_down(accc, off);
    }
    __shared__ float sr[4], sc[4];
    __shared__ bool sdone;
    int wid = t >> 6;
    if ((t & 63) == 0) { sr[wid] = accr; sc[wid] = accc; }
    __syncthreads();
    if (t == 0) {
        float r = sr[0] + sr[1] + sr[2] + sr[3];
        float c = sc[0] + sc[1] + sc[2] + sc[3];
        partials[(bc * 32 + ck) * 2 + 0] = r;   // layout: b*96 + c*32 + ck
        partials[(bc * 32 + ck) * 2 + 1] = c;
        __threadfence();
        unsigned int old = atomicAdd(counter, 1u);
        sdone = (old == 32u * 192u - 1u);
    }
    __syncthreads();
    if (sdone) {
        __threadfence();                 // acquire all partials
        if (t < 64) {
            float r = 0.f, c = 0.f;
            #pragma unroll
            for (int i = 0; i < 96; ++i) {       // fixed order -> deterministic
                r += partials[(t * 96 + i) * 2 + 0];
                c += partials[(t * 96 + i) * 2 + 1];
            }
            const float inv = 1.0f / (float)(CH * HW);
            r *= inv; c *= inv;
            out[t * 2 + 0] = 1.0f / (1.0f + expf(-c));   // col_out first
            out[t * 2 + 1] = 1.0f / (1.0f + expf(-r));
        }
        if (t == 0) *counter = 0u;       // self-reset for next replay
    }
}

extern "C" void kernel_launch(void* const* d_in, const int* in_sizes, int n_in,
                              void* d_out, int out_size, void* d_ws, size_t ws_size,
                              hipStream_t stream) {
    const float* x   = (const float*)d_in[0];   // [64,3,512,512]
    const float* att = (const float*)d_in[1];   // [512,512]
    const float* rw  = (const float*)d_in[2];   // [512]
    const float* cw  = (const float*)d_in[3];   // [512]
    float* out = (float*)d_out;                 // [64,2]

    float* ws = (float*)d_ws;
    float* Tr = ws;
    float* Tc = ws + 1 * MM;
    float* Gr = ws + 2 * MM;
    float* Gc = ws + 3 * MM;
    float* partials = ws + 4 * MM;              // 64*96*2 = 12288 floats
    unsigned int* counter = (unsigned int*)(ws + 4 * MM + 16384);

    k_stageA<<<1024, 256, 0, stream>>>(att, rw, cw, Tr, Tc, counter);
    k_stageB<<<1024, 256, 0, stream>>>(Tr, Tc, Gr, Gc);
    dim3 g(32, 192);
    k_reduce_final<<<g, 256, 0, stream>>>(x, Gr, Gc, partials, counter, out);
}

// Round 9
// 292.113 us; speedup vs baseline: 1.3782x; 1.3782x over previous
//
#include <hip/hip_runtime.h>
#include <math.h>

#define NN 512
#define MM (NN * NN)
#define HW (NN * NN)
#define CH 3

__device__ __forceinline__ float dct_s(int k) {
    // s_0 = sqrt(1/512), s_k = sqrt(2/512)
    return (k == 0) ? 0.04419417382415922f : 0.0625f;
}

// ---------------- Stage A: T[h][wp] ----------------
// Tr[h][wp] = sum_hp D[hp][h]*att[hp][wp]*rw[hp]
// Tc[h][wp] = cw[wp] * sum_hp D[hp][h]*att[hp][wp]
__global__ void __launch_bounds__(256) k_stageA(
    const float* __restrict__ att, const float* __restrict__ rw,
    const float* __restrict__ cw, float* __restrict__ Tr, float* __restrict__ Tc,
    unsigned int* __restrict__ counter)
{
    __shared__ float sD[2048];        // [hp][i] = D[hp][h0+i], computed in-kernel
    __shared__ float sRw[512];
    __shared__ float sAcc[256 * 9];   // pad 9 -> conflict-free k-reduction
    const int tid = threadIdx.x;
    const int bx  = blockIdx.x;
    if (bx == 0 && tid == 0) *counter = 0u;   // reset for fused reduce+final
    const int h0  = (bx >> 3) * 4;
    const int wp0 = (bx & 7) * 64;
    const int kc  = tid >> 6;
    const int wl  = tid & 63;
    const int wp  = wp0 + wl;
    const int hp0 = kc * 128;

    #pragma unroll
    for (int e = 0; e < 8; ++e) {                 // 2048 D entries, 8/thread
        int idx = tid * 8 + e;
        int hp = idx >> 2, i = idx & 3;
        int m = ((2 * (h0 + i) + 1) * hp) & 2047; // exact mod 4N
        sD[idx] = dct_s(hp) * cospif((float)m * (1.0f / 1024.0f));
    }
    sRw[tid] = rw[tid];
    sRw[256 + tid] = rw[256 + tid];
    __syncthreads();

    float ar0=0.f,ar1=0.f,ar2=0.f,ar3=0.f, as0=0.f,as1=0.f,as2=0.f,as3=0.f;
    #pragma unroll 4
    for (int t = 0; t < 128; ++t) {
        int hp = hp0 + t;
        float a = att[hp * NN + wp];              // coalesced 256B/wave
        float r = sRw[hp];                        // LDS broadcast
        float4 d = *reinterpret_cast<const float4*>(&sD[hp * 4]); // broadcast
        float ra = r * a;
        ar0 += d.x * ra; as0 += d.x * a;
        ar1 += d.y * ra; as1 += d.y * a;
        ar2 += d.z * ra; as2 += d.z * a;
        ar3 += d.w * ra; as3 += d.w * a;
    }
    float* sa = &sAcc[tid * 9];
    sa[0]=ar0; sa[1]=ar1; sa[2]=ar2; sa[3]=ar3;
    sa[4]=as0; sa[5]=as1; sa[6]=as2; sa[7]=as3;
    __syncthreads();
    if (tid < 64) {
        float v[8];
        #pragma unroll
        for (int j = 0; j < 8; ++j)
            v[j] = sAcc[(0*64 + tid)*9 + j] + sAcc[(1*64 + tid)*9 + j]
                 + sAcc[(2*64 + tid)*9 + j] + sAcc[(3*64 + tid)*9 + j];
        float c = cw[wp0 + tid];
        #pragma unroll
        for (int i = 0; i < 4; ++i) {
            Tr[(h0 + i) * NN + wp0 + tid] = v[i];
            Tc[(h0 + i) * NN + wp0 + tid] = v[4 + i] * c;
        }
    }
}

// ---------------- Stage B: G[h][w] = sum_wp T[h][wp] * D[wp][w] ----------------
__global__ void __launch_bounds__(256) k_stageB(
    const float* __restrict__ Tr, const float* __restrict__ Tc,
    float* __restrict__ Gr, float* __restrict__ Gc)
{
    __shared__ float sT[512 * 8];     // [wp][0..3]=Tr(h0..h0+3), [4..7]=Tc
    __shared__ float sAcc[256 * 9];
    const int tid = threadIdx.x;
    const int bx  = blockIdx.x;
    const int h0  = (bx >> 3) * 4;
    const int w0  = (bx & 7) * 64;
    const int kc  = tid >> 6;
    const int wl  = tid & 63;
    const int w   = w0 + wl;
    const int wp0 = kc * 128;

    #pragma unroll
    for (int i = 0; i < 4; ++i) {                 // coalesced global reads
        sT[tid * 8 + i]             = Tr[(h0 + i) * NN + tid];
        sT[tid * 8 + 4 + i]         = Tc[(h0 + i) * NN + tid];
        sT[(tid + 256) * 8 + i]     = Tr[(h0 + i) * NN + tid + 256];
        sT[(tid + 256) * 8 + 4 + i] = Tc[(h0 + i) * NN + tid + 256];
    }
    __syncthreads();

    float gr0=0.f,gr1=0.f,gr2=0.f,gr3=0.f, gc0=0.f,gc1=0.f,gc2=0.f,gc3=0.f;
    const int w2 = 2 * w + 1;
    int m = (w2 * wp0) & 2047;                    // incremental phase
    #pragma unroll 4
    for (int t = 0; t < 128; ++t) {
        int wp = wp0 + t;
        float s = (wp == 0) ? 0.04419417382415922f : 0.0625f;
        float d = s * cospif((float)m * (1.0f / 1024.0f));
        m = (m + w2) & 2047;
        float4 ta = *reinterpret_cast<const float4*>(&sT[wp * 8]);     // broadcast
        float4 tb = *reinterpret_cast<const float4*>(&sT[wp * 8 + 4]); // broadcast
        gr0 += ta.x * d; gr1 += ta.y * d; gr2 += ta.z * d; gr3 += ta.w * d;
        gc0 += tb.x * d; gc1 += tb.y * d; gc2 += tb.z * d; gc3 += tb.w * d;
    }
    float* sa = &sAcc[tid * 9];
    sa[0]=gr0; sa[1]=gr1; sa[2]=gr2; sa[3]=gr3;
    sa[4]=gc0; sa[5]=gc1; sa[6]=gc2; sa[7]=gc3;
    __syncthreads();
    if (tid < 64) {
        float v[8];
        #pragma unroll
        for (int j = 0; j < 8; ++j)
            v[j] = sAcc[(0*64 + tid)*9 + j] + sAcc[(1*64 + tid)*9 + j]
                 + sAcc[(2*64 + tid)*9 + j] + sAcc[(3*64 + tid)*9 + j];
        #pragma unroll
        for (int i = 0; i < 4; ++i) {
            Gr[(h0 + i) * NN + w0 + tid] = v[i];
            Gc[(h0 + i) * NN + w0 + tid] = v[4 + i];
        }
    }
}

// ---------------- Reduce + final (fused) ----------------
// grid (32, 192): block = (ck, b*3+c). One contiguous 32KB x stream per block,
// G chunks L2-resident. Plain (cached) loads — R8's nontemporal hint cut HBM
// fetch to 290 GB/s; removed.
__global__ void __launch_bounds__(256) k_reduce_final(
    const float* __restrict__ x, const float* __restrict__ Gr,
    const float* __restrict__ Gc, float* __restrict__ partials,
    unsigned int* __restrict__ counter, float* __restrict__ out)
{
    const int ck = blockIdx.x;        // 0..31
    const int bc = blockIdx.y;        // 0..191 = b*3 + c
    const int t  = threadIdx.x;
    const float* xp = x + (size_t)bc * HW;   // plane (b,c)
    const int hw0 = ck * (HW / 32);          // 8192-wide chunk

    float accr = 0.f, accc = 0.f;
    #pragma unroll
    for (int j = 0; j < 8; ++j) {
        int hw = hw0 + j * 1024 + t * 4;
        float4 xv = *(const float4*)(xp + hw);
        float4 gr = *(const float4*)(Gr + hw);
        float4 gc = *(const float4*)(Gc + hw);
        accr += gr.x * xv.x + gr.y * xv.y + gr.z * xv.z + gr.w * xv.w;
        accc += gc.x * xv.x + gc.y * xv.y + gc.z * xv.z + gc.w * xv.w;
    }
    for (int off = 32; off > 0; off >>= 1) {
        accr += __shfl_down(accr, off);
        accc += __shfl_down(accc, off);
    }
    __shared__ float sr[4], sc[4];
    __shared__ bool sdone;
    int wid = t >> 6;
    if ((t & 63) == 0) { sr[wid] = accr; sc[wid] = accc; }
    __syncthreads();
    if (t == 0) {
        float r = sr[0] + sr[1] + sr[2] + sr[3];
        float c = sc[0] + sc[1] + sc[2] + sc[3];
        partials[(bc * 32 + ck) * 2 + 0] = r;   // layout: b*96 + c*32 + ck
        partials[(bc * 32 + ck) * 2 + 1] = c;
        __threadfence();
        unsigned int old = atomicAdd(counter, 1u);
        sdone = (old == 32u * 192u - 1u);
    }
    __syncthreads();
    if (sdone) {
        __threadfence();                 // acquire all partials
        if (t < 64) {
            float r = 0.f, c = 0.f;
            #pragma unroll
            for (int i = 0; i < 96; ++i) {       // fixed order -> deterministic
                r += partials[(t * 96 + i) * 2 + 0];
                c += partials[(t * 96 + i) * 2 + 1];
            }
            const float inv = 1.0f / (float)(CH * HW);
            r *= inv; c *= inv;
            out[t * 2 + 0] = 1.0f / (1.0f + expf(-c));   // col_out first
            out[t * 2 + 1] = 1.0f / (1.0f + expf(-r));
        }
        if (t == 0) *counter = 0u;       // self-reset for next replay
    }
}

extern "C" void kernel_launch(void* const* d_in, const int* in_sizes, int n_in,
                              void* d_out, int out_size, void* d_ws, size_t ws_size,
                              hipStream_t stream) {
    const float* x   = (const float*)d_in[0];   // [64,3,512,512]
    const float* att = (const float*)d_in[1];   // [512,512]
    const float* rw  = (const float*)d_in[2];   // [512]
    const float* cw  = (const float*)d_in[3];   // [512]
    float* out = (float*)d_out;                 // [64,2]

    float* ws = (float*)d_ws;
    float* Tr = ws;
    float* Tc = ws + 1 * MM;
    float* Gr = ws + 2 * MM;
    float* Gc = ws + 3 * MM;
    float* partials = ws + 4 * MM;              // 64*96*2 = 12288 floats
    unsigned int* counter = (unsigned int*)(ws + 4 * MM + 16384);

    k_stageA<<<1024, 256, 0, stream>>>(att, rw, cw, Tr, Tc, counter);
    k_stageB<<<1024, 256, 0, stream>>>(Tr, Tc, Gr, Gc);
    dim3 g(32, 192);
    k_reduce_final<<<g, 256, 0, stream>>>(x, Gr, Gc, partials, counter, out);
}

// Round 10
// 85.500 us; speedup vs baseline: 4.7086x; 3.4165x over previous
//
#include <hip/hip_runtime.h>
#include <math.h>

#define NN 512
#define MM (NN * NN)
#define HW (NN * NN)
#define CH 3

__device__ __forceinline__ float dct_s(int k) {
    // s_0 = sqrt(1/512), s_k = sqrt(2/512)
    return (k == 0) ? 0.04419417382415922f : 0.0625f;
}

// ---------------- Stage A: T[h][wp] ----------------
// Tr[h][wp] = sum_hp D[hp][h]*att[hp][wp]*rw[hp]
// Tc[h][wp] = cw[wp] * sum_hp D[hp][h]*att[hp][wp]
__global__ void __launch_bounds__(256) k_stageA(
    const float* __restrict__ att, const float* __restrict__ rw,
    const float* __restrict__ cw, float* __restrict__ Tr, float* __restrict__ Tc)
{
    __shared__ float sD[2048];        // [hp][i] = D[hp][h0+i], computed in-kernel
    __shared__ float sRw[512];
    __shared__ float sAcc[256 * 9];   // pad 9 -> conflict-free k-reduction
    const int tid = threadIdx.x;
    const int bx  = blockIdx.x;
    const int h0  = (bx >> 3) * 4;
    const int wp0 = (bx & 7) * 64;
    const int kc  = tid >> 6;
    const int wl  = tid & 63;
    const int wp  = wp0 + wl;
    const int hp0 = kc * 128;

    #pragma unroll
    for (int e = 0; e < 8; ++e) {                 // 2048 D entries, 8/thread
        int idx = tid * 8 + e;
        int hp = idx >> 2, i = idx & 3;
        int m = ((2 * (h0 + i) + 1) * hp) & 2047; // exact mod 4N
        sD[idx] = dct_s(hp) * cospif((float)m * (1.0f / 1024.0f));
    }
    sRw[tid] = rw[tid];
    sRw[256 + tid] = rw[256 + tid];
    __syncthreads();

    float ar0=0.f,ar1=0.f,ar2=0.f,ar3=0.f, as0=0.f,as1=0.f,as2=0.f,as3=0.f;
    #pragma unroll 4
    for (int t = 0; t < 128; ++t) {
        int hp = hp0 + t;
        float a = att[hp * NN + wp];              // coalesced 256B/wave
        float r = sRw[hp];                        // LDS broadcast
        float4 d = *reinterpret_cast<const float4*>(&sD[hp * 4]); // broadcast
        float ra = r * a;
        ar0 += d.x * ra; as0 += d.x * a;
        ar1 += d.y * ra; as1 += d.y * a;
        ar2 += d.z * ra; as2 += d.z * a;
        ar3 += d.w * ra; as3 += d.w * a;
    }
    float* sa = &sAcc[tid * 9];
    sa[0]=ar0; sa[1]=ar1; sa[2]=ar2; sa[3]=ar3;
    sa[4]=as0; sa[5]=as1; sa[6]=as2; sa[7]=as3;
    __syncthreads();
    if (tid < 64) {
        float v[8];
        #pragma unroll
        for (int j = 0; j < 8; ++j)
            v[j] = sAcc[(0*64 + tid)*9 + j] + sAcc[(1*64 + tid)*9 + j]
                 + sAcc[(2*64 + tid)*9 + j] + sAcc[(3*64 + tid)*9 + j];
        float c = cw[wp0 + tid];
        #pragma unroll
        for (int i = 0; i < 4; ++i) {
            Tr[(h0 + i) * NN + wp0 + tid] = v[i];
            Tc[(h0 + i) * NN + wp0 + tid] = v[4 + i] * c;
        }
    }
}

// ---------------- Stage B: G[h][w] = sum_wp T[h][wp] * D[wp][w] ----------------
__global__ void __launch_bounds__(256) k_stageB(
    const float* __restrict__ Tr, const float* __restrict__ Tc,
    float* __restrict__ Gr, float* __restrict__ Gc)
{
    __shared__ float sT[512 * 8];     // [wp][0..3]=Tr(h0..h0+3), [4..7]=Tc
    __shared__ float sAcc[256 * 9];
    const int tid = threadIdx.x;
    const int bx  = blockIdx.x;
    const int h0  = (bx >> 3) * 4;
    const int w0  = (bx & 7) * 64;
    const int kc  = tid >> 6;
    const int wl  = tid & 63;
    const int w   = w0 + wl;
    const int wp0 = kc * 128;

    #pragma unroll
    for (int i = 0; i < 4; ++i) {                 // coalesced global reads
        sT[tid * 8 + i]             = Tr[(h0 + i) * NN + tid];
        sT[tid * 8 + 4 + i]         = Tc[(h0 + i) * NN + tid];
        sT[(tid + 256) * 8 + i]     = Tr[(h0 + i) * NN + tid + 256];
        sT[(tid + 256) * 8 + 4 + i] = Tc[(h0 + i) * NN + tid + 256];
    }
    __syncthreads();

    float gr0=0.f,gr1=0.f,gr2=0.f,gr3=0.f, gc0=0.f,gc1=0.f,gc2=0.f,gc3=0.f;
    const int w2 = 2 * w + 1;
    int m = (w2 * wp0) & 2047;                    // incremental phase
    #pragma unroll 4
    for (int t = 0; t < 128; ++t) {
        int wp = wp0 + t;
        float s = (wp == 0) ? 0.04419417382415922f : 0.0625f;
        float d = s * cospif((float)m * (1.0f / 1024.0f));
        m = (m + w2) & 2047;
        float4 ta = *reinterpret_cast<const float4*>(&sT[wp * 8]);     // broadcast
        float4 tb = *reinterpret_cast<const float4*>(&sT[wp * 8 + 4]); // broadcast
        gr0 += ta.x * d; gr1 += ta.y * d; gr2 += ta.z * d; gr3 += ta.w * d;
        gc0 += tb.x * d; gc1 += tb.y * d; gc2 += tb.z * d; gc3 += tb.w * d;
    }
    float* sa = &sAcc[tid * 9];
    sa[0]=gr0; sa[1]=gr1; sa[2]=gr2; sa[3]=gr3;
    sa[4]=gc0; sa[5]=gc1; sa[6]=gc2; sa[7]=gc3;
    __syncthreads();
    if (tid < 64) {
        float v[8];
        #pragma unroll
        for (int j = 0; j < 8; ++j)
            v[j] = sAcc[(0*64 + tid)*9 + j] + sAcc[(1*64 + tid)*9 + j]
                 + sAcc[(2*64 + tid)*9 + j] + sAcc[(3*64 + tid)*9 + j];
        #pragma unroll
        for (int i = 0; i < 4; ++i) {
            Gr[(h0 + i) * NN + w0 + tid] = v[i];
            Gc[(h0 + i) * NN + w0 + tid] = v[4 + i];
        }
    }
}

// ---------------- Reduce: per-b dot with Gr/Gc ----------------
// grid (32, 64): 2048 blocks (8/CU). Blocks sharing a ck (stride-32 apart) land
// on the SAME XCD -> G chunk L2-resident. 2-deep load-then-compute pipeline
// (10 independent float4 loads in flight); launch_bounds(256,8) keeps VGPR<=64
// so all 8 blocks/CU stay resident. No fences, no atomics (R6-R9 lesson).
__global__ void __launch_bounds__(256, 8) k_reduce(
    const float* __restrict__ x, const float* __restrict__ Gr,
    const float* __restrict__ Gc, float* __restrict__ partials)
{
    const int b = blockIdx.y, ck = blockIdx.x, t = threadIdx.x;
    const float* xb = x + (size_t)b * (CH * HW);
    const int base = ck * (HW / 32) + t * 4;      // 8192-wide chunk
    float accr = 0.f, accc = 0.f;
    #pragma unroll
    for (int g = 0; g < 4; ++g) {
        const int hw0 = base + (2 * g) * 1024;
        const int hw1 = base + (2 * g + 1) * 1024;
        // issue all 10 loads of the group before consuming
        float4 gr0 = *(const float4*)(Gr + hw0);
        float4 gc0 = *(const float4*)(Gc + hw0);
        float4 a0 = *(const float4*)(xb + hw0);
        float4 a1 = *(const float4*)(xb + HW + hw0);
        float4 a2 = *(const float4*)(xb + 2 * HW + hw0);
        float4 gr1 = *(const float4*)(Gr + hw1);
        float4 gc1 = *(const float4*)(Gc + hw1);
        float4 b0 = *(const float4*)(xb + hw1);
        float4 b1 = *(const float4*)(xb + HW + hw1);
        float4 b2 = *(const float4*)(xb + 2 * HW + hw1);
        float s0x = a0.x + a1.x + a2.x, s0y = a0.y + a1.y + a2.y;
        float s0z = a0.z + a1.z + a2.z, s0w = a0.w + a1.w + a2.w;
        accr += gr0.x * s0x + gr0.y * s0y + gr0.z * s0z + gr0.w * s0w;
        accc += gc0.x * s0x + gc0.y * s0y + gc0.z * s0z + gc0.w * s0w;
        float s1x = b0.x + b1.x + b2.x, s1y = b0.y + b1.y + b2.y;
        float s1z = b0.z + b1.z + b2.z, s1w = b0.w + b1.w + b2.w;
        accr += gr1.x * s1x + gr1.y * s1y + gr1.z * s1z + gr1.w * s1w;
        accc += gc1.x * s1x + gc1.y * s1y + gc1.z * s1z + gc1.w * s1w;
    }
    for (int off = 32; off > 0; off >>= 1) {
        accr += __shfl_down(accr, off);
        accc += __shfl_down(accc, off);
    }
    __shared__ float sr[4], sc[4];
    int wid = t >> 6;
    if ((t & 63) == 0) { sr[wid] = accr; sc[wid] = accc; }
    __syncthreads();
    if (t == 0) {
        partials[(b * 32 + ck) * 2 + 0] = sr[0] + sr[1] + sr[2] + sr[3];
        partials[(b * 32 + ck) * 2 + 1] = sc[0] + sc[1] + sc[2] + sc[3];
    }
}

__global__ void k_final(const float* __restrict__ partials, float* __restrict__ out) {
    int b = threadIdx.x;   // 0..63
    float r = 0.f, c = 0.f;
    for (int i = 0; i < 32; ++i) {
        r += partials[(b * 32 + i) * 2 + 0];
        c += partials[(b * 32 + i) * 2 + 1];
    }
    const float inv = 1.0f / (float)(CH * HW);
    r *= inv; c *= inv;
    out[b * 2 + 0] = 1.0f / (1.0f + expf(-c));   // col_out first (stack order)
    out[b * 2 + 1] = 1.0f / (1.0f + expf(-r));
}

extern "C" void kernel_launch(void* const* d_in, const int* in_sizes, int n_in,
                              void* d_out, int out_size, void* d_ws, size_t ws_size,
                              hipStream_t stream) {
    const float* x   = (const float*)d_in[0];   // [64,3,512,512]
    const float* att = (const float*)d_in[1];   // [512,512]
    const float* rw  = (const float*)d_in[2];   // [512]
    const float* cw  = (const float*)d_in[3];   // [512]
    float* out = (float*)d_out;                 // [64,2]

    float* ws = (float*)d_ws;
    float* Tr = ws;
    float* Tc = ws + 1 * MM;
    float* Gr = ws + 2 * MM;
    float* Gc = ws + 3 * MM;
    float* partials = ws + 4 * MM;              // 64*32*2 = 4096

    k_stageA<<<1024, 256, 0, stream>>>(att, rw, cw, Tr, Tc);
    k_stageB<<<1024, 256, 0, stream>>>(Tr, Tc, Gr, Gc);
    dim3 g(32, 64);
    k_reduce<<<g, 256, 0, stream>>>(x, Gr, Gc, partials);
    k_final<<<1, 64, 0, stream>>>(partials, out);
}